// Round 3
// baseline (1512.597 us; speedup 1.0000x reference)
//
#include <hip/hip_runtime.h>
#include <hip/hip_bf16.h>
#include <math.h>

typedef __bf16 bf16;
typedef __bf16 bf16x8 __attribute__((ext_vector_type(8)));
typedef __bf16 bf16x4 __attribute__((ext_vector_type(4)));
typedef float  f32x4  __attribute__((ext_vector_type(4)));

#define DEV __device__ __forceinline__

DEV f32x4 mfma16(bf16x8 a, bf16x8 b, f32x4 c) {
    return __builtin_amdgcn_mfma_f32_16x16x32_bf16(a, b, c, 0, 0, 0);
}

// async 16B global->LDS. LDS dest is wave-uniform base + lane*16 (linear!).
DEV void gload16(const bf16* g, bf16* l) {
    __builtin_amdgcn_global_load_lds(
        (const __attribute__((address_space(1))) void*)g,
        (__attribute__((address_space(3))) void*)l, 16, 0, 0);
}

// exact-enough erf: Abramowitz-Stegun 7.1.26, |err| <= 1.5e-7 (<< bf16 ulp)
DEV float gelu_f(float v) {
    float xs = v * 0.70710678118654752f;
    float ax = fabsf(xs);
    float t  = 1.0f / (1.0f + 0.3275911f * ax);
    float p  = t * (0.254829592f + t * (-0.284496736f + t * (1.421413741f +
               t * (-1.453152027f + t * 1.061405429f))));
    float er = 1.0f - p * __expf(-ax * ax);
    er = copysignf(er, xs);
    return 0.5f * v * (1.0f + er);
}

// ---------------------------------------------------------------------------
// Wide GEMM: C[M x N] = A[M x K] @ Bt[N x K]^T (+fp32 bias), 128x128, BK=32,
// double-buffered LDS + single barrier per K-step; global_load_lds width=16
// with chunk-XOR swizzle pre-applied to the GLOBAL source (both-sides rule).
// MODE 1: Cb = gelu(acc + bias).
// MODE 2 (QKV): cols <1024 (Q,K) -> Cb[ldC]; V tiles (tn>=1024) -> vt in
//   [(b*8+h)*64+d][n] layout via LDS transpose (coalesced 16B stores).
// ---------------------------------------------------------------------------
template <int MODE>
__global__ __launch_bounds__(256, 3) void gemm_k(
    const bf16* __restrict__ A, const bf16* __restrict__ Bt,
    const float* __restrict__ bias, bf16* __restrict__ Cb,
    bf16* __restrict__ vt, int K, int ldC)
{
    __shared__ bf16 smem[(MODE == 2) ? 17408 : 16384];
    bf16* As = smem;            // [2][4096]
    bf16* Bs = smem + 8192;     // [2][4096]

    const int tid  = threadIdx.x;
    const int lane = tid & 63;
    const int w    = tid >> 6;
    const int wm   = w & 1, wn = w >> 1;
    const long tm  = (long)blockIdx.y * 128;
    const long tn  = (long)blockIdx.x * 128;

    f32x4 acc[4][4] = {};

    const int r0 = tid >> 2;
    const int cc = ((tid & 3) ^ ((r0 >> 1) & 3)) * 8;
    const bf16* Ag = A  + (tm + r0) * K + cc;
    const bf16* Bg = Bt + (tn + r0) * K + cc;
    const long rstep = (long)64 * K;

    int am[4], bn[4];
#pragma unroll
    for (int i = 0; i < 4; ++i) {
        int ra = wm * 64 + i * 16 + (lane & 15);
        am[i]  = ra * 32 + (((lane >> 4) ^ ((ra >> 1) & 3)) * 8);
        int rb = wn * 64 + i * 16 + (lane & 15);
        bn[i]  = rb * 32 + (((lane >> 4) ^ ((rb >> 1) & 3)) * 8);
    }

#define STAGE(buf, kk)                                        \
    do {                                                      \
        gload16(Ag + (kk),         &As[(buf)*4096 + tid*8]);  \
        gload16(Ag + rstep + (kk), &As[(buf)*4096 + 2048 + tid*8]); \
        gload16(Bg + (kk),         &Bs[(buf)*4096 + tid*8]);  \
        gload16(Bg + rstep + (kk), &Bs[(buf)*4096 + 2048 + tid*8]); \
    } while (0)

#define COMPUTE(buf)                                                    \
    do {                                                                \
        bf16x8 a[4], b[4];                                              \
        _Pragma("unroll")                                               \
        for (int i = 0; i < 4; ++i) a[i] = *(const bf16x8*)&As[(buf)*4096 + am[i]]; \
        _Pragma("unroll")                                               \
        for (int i = 0; i < 4; ++i) b[i] = *(const bf16x8*)&Bs[(buf)*4096 + bn[i]]; \
        _Pragma("unroll")                                               \
        for (int mi = 0; mi < 4; ++mi)                                  \
            _Pragma("unroll")                                           \
            for (int ni = 0; ni < 4; ++ni)                              \
                acc[mi][ni] = mfma16(a[mi], b[ni], acc[mi][ni]);        \
    } while (0)

    STAGE(0, 0);
    __syncthreads();
    for (int k0 = 0; k0 < K; k0 += 64) {
        STAGE(1, k0 + 32);
        COMPUTE(0);
        __syncthreads();
        if (k0 + 64 < K) STAGE(0, k0 + 64);
        COMPUTE(1);
        __syncthreads();
    }

    bool vpath = false;
    if constexpr (MODE == 2) vpath = (tn >= 1024);

    if (vpath) {
        bf16* Ct = smem;  // [128 cols][136 rows]
#pragma unroll
        for (int mi = 0; mi < 4; ++mi) {
            const int rowL = wm * 64 + mi * 16 + ((lane >> 4) << 2);
#pragma unroll
            for (int ni = 0; ni < 4; ++ni) {
                const int colL = wn * 64 + ni * 16 + (lane & 15);
                const float bv = bias[tn + colL];
                bf16x4 pk;
#pragma unroll
                for (int r = 0; r < 4; ++r) pk[r] = (bf16)(acc[mi][ni][r] + bv);
                *(bf16x4*)&Ct[colL * 136 + rowL] = pk;
            }
        }
        __syncthreads();
        const int b_blk = (int)(tm >> 8);
        const int nin   = (int)(tm & 255);
        const int cvb   = (int)(tn - 1024);
#pragma unroll
        for (int j = 0; j < 8; ++j) {
            int idx = j * 256 + tid;
            int c   = idx >> 4;
            int nc  = (idx & 15) * 8;
            bf16x8 vv = *(const bf16x8*)&Ct[c * 136 + nc];
            int cv = cvb + c;
            *(bf16x8*)&vt[(((long)b_blk * 8 + (cv >> 6)) * 64 + (cv & 63)) * 256 + nin + nc] = vv;
        }
        return;
    }

#pragma unroll
    for (int mi = 0; mi < 4; ++mi) {
        const long rbase = tm + wm * 64 + mi * 16 + ((lane >> 4) << 2);
#pragma unroll
        for (int ni = 0; ni < 4; ++ni) {
            const long col = tn + wn * 64 + ni * 16 + (lane & 15);
            const float bv = bias[col];
#pragma unroll
            for (int r = 0; r < 4; ++r) {
                float v = acc[mi][ni][r] + bv;
                if constexpr (MODE == 1) v = gelu_f(v);
                Cb[(rbase + r) * (long)ldC + col] = (bf16)v;
            }
        }
    }
#undef STAGE
#undef COMPUTE
}

// ---------------------------------------------------------------------------
// Split-K delta GEMM (N=512): 128x64 tile -> grid 8x64x2 = 1024 blocks
// (4 blocks/CU instead of 2; R2 counters: dk occupancy was grid-capped).
// Wave tile 64x32, acc[4][2]. LDS 24 KB dbuf.
// ---------------------------------------------------------------------------
__global__ __launch_bounds__(256, 4) void gemm_dk(
    const bf16* __restrict__ A, const bf16* __restrict__ Bt,
    bf16* __restrict__ D, int K, int Ks)
{
    __shared__ bf16 smem[8192 + 4096];
    bf16* As = smem;           // [2][4096]
    bf16* Bs = smem + 8192;    // [2][2048]

    const int tid  = threadIdx.x;
    const int lane = tid & 63;
    const int w    = tid >> 6;
    const int wm   = w & 1, wn = w >> 1;
    const long tm  = (long)blockIdx.y * 128;
    const long tn  = (long)blockIdx.x * 64;
    const int kbase = blockIdx.z * Ks;

    f32x4 acc[4][2] = {};

    const int r0 = tid >> 2;
    const int cc = ((tid & 3) ^ ((r0 >> 1) & 3)) * 8;
    const bf16* Ag = A  + (tm + r0) * K + kbase + cc;
    const bf16* Bg = Bt + (tn + r0) * K + kbase + cc;
    const long rstep = (long)64 * K;

    int am[4], bn[2];
#pragma unroll
    for (int i = 0; i < 4; ++i) {
        int ra = wm * 64 + i * 16 + (lane & 15);
        am[i]  = ra * 32 + (((lane >> 4) ^ ((ra >> 1) & 3)) * 8);
    }
#pragma unroll
    for (int i = 0; i < 2; ++i) {
        int rb = wn * 32 + i * 16 + (lane & 15);
        bn[i]  = rb * 32 + (((lane >> 4) ^ ((rb >> 1) & 3)) * 8);
    }

#define STAGE(buf, kk)                                        \
    do {                                                      \
        gload16(Ag + (kk),         &As[(buf)*4096 + tid*8]);  \
        gload16(Ag + rstep + (kk), &As[(buf)*4096 + 2048 + tid*8]); \
        gload16(Bg + (kk),         &Bs[(buf)*2048 + tid*8]);  \
    } while (0)

#define COMPUTE(buf)                                                    \
    do {                                                                \
        bf16x8 a[4], b[2];                                              \
        _Pragma("unroll")                                               \
        for (int i = 0; i < 4; ++i) a[i] = *(const bf16x8*)&As[(buf)*4096 + am[i]]; \
        _Pragma("unroll")                                               \
        for (int i = 0; i < 2; ++i) b[i] = *(const bf16x8*)&Bs[(buf)*2048 + bn[i]]; \
        _Pragma("unroll")                                               \
        for (int mi = 0; mi < 4; ++mi)                                  \
            _Pragma("unroll")                                           \
            for (int ni = 0; ni < 2; ++ni)                              \
                acc[mi][ni] = mfma16(a[mi], b[ni], acc[mi][ni]);        \
    } while (0)

    STAGE(0, 0);
    __syncthreads();
    for (int k0 = 0; k0 < Ks; k0 += 64) {
        STAGE(1, k0 + 32);
        COMPUTE(0);
        __syncthreads();
        if (k0 + 64 < Ks) STAGE(0, k0 + 64);
        COMPUTE(1);
        __syncthreads();
    }

    bf16* Dp = D + (long)blockIdx.z * 8192 * 512;
#pragma unroll
    for (int mi = 0; mi < 4; ++mi) {
        const long rbase = tm + wm * 64 + mi * 16 + ((lane >> 4) << 2);
#pragma unroll
        for (int ni = 0; ni < 2; ++ni) {
            const long col = tn + wn * 32 + ni * 16 + (lane & 15);
#pragma unroll
            for (int r = 0; r < 4; ++r)
                Dp[(rbase + r) * 512 + col] = (bf16)acc[mi][ni][r];
        }
    }
#undef STAGE
#undef COMPUTE
}

// ---------------------------------------------------------------------------
// Attention, swapped-QK form: compute S^T = K·Q^T so the C fragment is
// [row=k][col=q]. Bias then loads as aligned float4 (4 consecutive k per
// lane) instead of 64 scalar f32 loads -- R2 counters showed attn_k is
// bias-load-bound (FETCH 69.7 MB ~= the f32 bias slice, 1.9 TB/s).
// Softmax: in-lane over 64 vals + 2 shuffles (xor16/32). 1/l folded into P.
// ---------------------------------------------------------------------------
__global__ __launch_bounds__(256, 4) void attn_k(
    const bf16* __restrict__ qkv, const bf16* __restrict__ vt,
    const float* __restrict__ bias, bf16* __restrict__ ctx)
{
    __shared__ bf16 smem[256 * 72];
    bf16* Ks = smem;

    const int tid = threadIdx.x, lane = tid & 63, w = tid >> 6;
    const int qt = blockIdx.x & 3;
    const int h  = (blockIdx.x >> 2) & 7;
    const int b  = blockIdx.x >> 5;
    const long qkv_base = (long)b * 256 * 1536;

#pragma unroll
    for (int i = 0; i < 8; ++i) {
        int p = i * 256 + tid;
        int n = p >> 3, kk = (p & 7) * 8;
        uint4 v = *(const uint4*)(qkv + qkv_base + (long)n * 1536 + 512 + h * 64 + kk);
        *(uint4*)&Ks[n * 72 + kk] = v;
    }

    const int qr0 = qt * 64 + w * 16;
    bf16x8 aq0, aq1;
    {
        const bf16* g = qkv + qkv_base + (long)(qr0 + (lane & 15)) * 1536 + h * 64 + ((lane >> 4) * 8);
        aq0 = *(const bf16x8*)g;
        aq1 = *(const bf16x8*)(g + 32);
    }
    __syncthreads();

    // S^T: per lane q = lane&15 fixed, k = ct*16 + (lane>>4)*4 + r
    f32x4 s[16];
    const float* bq_ = bias + ((((long)(b * 8 + h)) * 256 + qr0 + (lane & 15)) * 256)
                     + ((lane >> 4) * 4);
#pragma unroll
    for (int ct = 0; ct < 16; ++ct) {
        f32x4 c = *(const f32x4*)(bq_ + ct * 16);
        bf16x8 k0 = *(const bf16x8*)&Ks[(ct * 16 + (lane & 15)) * 72 + ((lane >> 4) * 8)];
        bf16x8 k1 = *(const bf16x8*)&Ks[(ct * 16 + (lane & 15)) * 72 + 32 + ((lane >> 4) * 8)];
        c = mfma16(k0, aq0, c);   // A = K tile, B = Q tile  ->  C = S^T
        c = mfma16(k1, aq1, c);
        s[ct] = c;
    }

    float m = -1e30f;
#pragma unroll
    for (int ct = 0; ct < 16; ++ct)
#pragma unroll
        for (int r = 0; r < 4; ++r) m = fmaxf(m, s[ct][r]);
    m = fmaxf(m, __shfl_xor(m, 16));
    m = fmaxf(m, __shfl_xor(m, 32));

    float l = 0.f;
#pragma unroll
    for (int ct = 0; ct < 16; ++ct)
#pragma unroll
        for (int r = 0; r < 4; ++r) {
            float p = __expf(s[ct][r] - m);
            s[ct][r] = p;
            l += p;
        }
    l += __shfl_xor(l, 16);
    l += __shfl_xor(l, 32);
    const float linv = 1.0f / l;

    __syncthreads();
    bf16* P = smem + w * (16 * 264);
#pragma unroll
    for (int ct = 0; ct < 16; ++ct) {
        bf16x4 pk;
#pragma unroll
        for (int r = 0; r < 4; ++r) pk[r] = (bf16)(s[ct][r] * linv);
        *(bf16x4*)&P[(lane & 15) * 264 + ct * 16 + ((lane >> 4) * 4)] = pk;
    }

    bf16x8 ap[8];
#pragma unroll
    for (int nk = 0; nk < 8; ++nk)
        ap[nk] = *(const bf16x8*)&P[(lane & 15) * 264 + nk * 32 + (lane >> 4) * 8];

    const bf16* vg = vt + (long)(b * 8 + h) * 64 * 256;
    f32x4 o[4];
#pragma unroll
    for (int dt = 0; dt < 4; ++dt) {
        f32x4 c = {};
#pragma unroll
        for (int nk = 0; nk < 8; ++nk) {
            bf16x8 bv = *(const bf16x8*)&vg[(dt * 16 + (lane & 15)) * 256 + nk * 32 + (lane >> 4) * 8];
            c = mfma16(ap[nk], bv, c);
        }
        o[dt] = c;
    }

#pragma unroll
    for (int dt = 0; dt < 4; ++dt) {
        const int col = h * 64 + dt * 16 + (lane & 15);
#pragma unroll
        for (int r = 0; r < 4; ++r) {
            const long row = (long)b * 256 + qr0 + (lane >> 4) * 4 + r;
            ctx[row * 512 + col] = (bf16)o[dt][r];
        }
    }
}

// ---------------------------------------------------------------------------
// Fused residual-add + LayerNorm. NS = number of bf16 delta slices (0 or 2).
// ---------------------------------------------------------------------------
template <int NS>
__global__ __launch_bounds__(256) void ln_k(
    const float* __restrict__ x, float* __restrict__ xout,
    const bf16* __restrict__ d, const float* __restrict__ rbias,
    const float* __restrict__ sc, const float* __restrict__ bi,
    bf16* __restrict__ y)
{
    const int lane = threadIdx.x & 63;
    const long row = (long)blockIdx.x * 4 + (threadIdx.x >> 6);
    const float* xr = x + row * 512;
    float v[8];
    *(float4*)&v[0] = ((const float4*)xr)[lane * 2];
    *(float4*)&v[4] = ((const float4*)xr)[lane * 2 + 1];
    if constexpr (NS == 2) {
        bf16x8 d0 = *(const bf16x8*)&d[row * 512 + lane * 8];
        bf16x8 d1 = *(const bf16x8*)&d[(long)8192 * 512 + row * 512 + lane * 8];
        float b4[8];
        *(float4*)&b4[0] = ((const float4*)rbias)[lane * 2];
        *(float4*)&b4[4] = ((const float4*)rbias)[lane * 2 + 1];
#pragma unroll
        for (int j = 0; j < 8; ++j)
            v[j] += (float)d0[j] + (float)d1[j] + b4[j];
        float* xo = xout + row * 512;
        ((float4*)xo)[lane * 2]     = *(const float4*)&v[0];
        ((float4*)xo)[lane * 2 + 1] = *(const float4*)&v[4];
    }
    float sum = 0.f;
#pragma unroll
    for (int j = 0; j < 8; ++j) sum += v[j];
#pragma unroll
    for (int off = 1; off < 64; off <<= 1) sum += __shfl_xor(sum, off);
    const float mu = sum * (1.0f / 512.0f);
    float sq = 0.f;
#pragma unroll
    for (int j = 0; j < 8; ++j) { float dd = v[j] - mu; sq += dd * dd; }
#pragma unroll
    for (int off = 1; off < 64; off <<= 1) sq += __shfl_xor(sq, off);
    const float rs = rsqrtf(sq * (1.0f / 512.0f) + 1e-5f);
    bf16* yr = y + row * 512;
#pragma unroll
    for (int j = 0; j < 8; ++j) {
        int c = lane * 8 + j;
        yr[c] = (bf16)((v[j] - mu) * rs * sc[c] + bi[c]);
    }
}

// final: out = xf + d0 + d1 + rbias (fp32)
__global__ __launch_bounds__(256) void addout_k(
    const float* __restrict__ x, const bf16* __restrict__ d,
    const float* __restrict__ rbias, float* __restrict__ out)
{
    const int lane = threadIdx.x & 63;
    const long row = (long)blockIdx.x * 4 + (threadIdx.x >> 6);
    float v[8];
    *(float4*)&v[0] = ((const float4*)(x + row * 512))[lane * 2];
    *(float4*)&v[4] = ((const float4*)(x + row * 512))[lane * 2 + 1];
    bf16x8 d0 = *(const bf16x8*)&d[row * 512 + lane * 8];
    bf16x8 d1 = *(const bf16x8*)&d[(long)8192 * 512 + row * 512 + lane * 8];
    float b4[8];
    *(float4*)&b4[0] = ((const float4*)rbias)[lane * 2];
    *(float4*)&b4[4] = ((const float4*)rbias)[lane * 2 + 1];
#pragma unroll
    for (int j = 0; j < 8; ++j)
        v[j] += (float)d0[j] + (float)d1[j] + b4[j];
    float* o = out + row * 512;
    ((float4*)o)[lane * 2]     = *(const float4*)&v[0];
    ((float4*)o)[lane * 2 + 1] = *(const float4*)&v[4];
}

// ---------------------------------------------------------------------------
// One-shot weight transpose fp32 -> bf16 [N][K] layout (q-scale folded).
// ---------------------------------------------------------------------------
__global__ __launch_bounds__(256) void transpose_k(
    const float* __restrict__ wq, const float* __restrict__ wk,
    const float* __restrict__ wv, const float* __restrict__ wo,
    const float* __restrict__ w1, const float* __restrict__ w2,
    bf16* __restrict__ qkvT, bf16* __restrict__ woT,
    bf16* __restrict__ w1T, bf16* __restrict__ w2T)
{
    __shared__ float tile[32][33];
    const int tid = threadIdx.x, tx = tid & 31, ty = tid >> 5;
    const int l = blockIdx.x / 3072;
    const int r = blockIdx.x % 3072;

    const float* In = nullptr;
    bf16* Out = nullptr;
    int Nd, tk, tn, rowOff = 0, ldO;
    float scale = 1.0f;
    if (r < 1024) {
        const int which = r >> 8, t = r & 255;
        tn = t >> 4; tk = t & 15; Nd = 512; ldO = 512;
        const long woff = (long)l * 512 * 512;
        if (which == 0)      { In = wq + woff; Out = qkvT + (long)l * 1536 * 512; rowOff = 0;    scale = 0.125f; }
        else if (which == 1) { In = wk + woff; Out = qkvT + (long)l * 1536 * 512; rowOff = 512;  }
        else if (which == 2) { In = wv + woff; Out = qkvT + (long)l * 1536 * 512; rowOff = 1024; }
        else                 { In = wo + woff; Out = woT + woff; }
    } else if (r < 2048) {
        const int t = r - 1024;
        tn = t >> 4; tk = t & 15; Nd = 2048; ldO = 512;
        In = w1 + (long)l * 512 * 2048; Out = w1T + (long)l * 2048 * 512;
    } else {
        const int t = r - 2048;
        tn = t & 15; tk = t >> 4; Nd = 512; ldO = 2048;
        In = w2 + (long)l * 2048 * 512; Out = w2T + (long)l * 512 * 2048;
    }
    const int gk = tk * 32, gn = tn * 32;
#pragma unroll
    for (int j = 0; j < 4; ++j) {
        int rr = ty + j * 8;
        tile[rr][tx] = In[(long)(gk + rr) * Nd + gn + tx] * scale;
    }
    __syncthreads();
#pragma unroll
    for (int j = 0; j < 4; ++j) {
        int rr = ty + j * 8;
        Out[(long)(rowOff + gn + rr) * ldO + gk + tx] = (bf16)tile[tx][rr];
    }
}

__global__ void biasq_k(const float* __restrict__ bq, const float* __restrict__ bk,
                        const float* __restrict__ bv, float* __restrict__ bqkv)
{
    int i = blockIdx.x * 256 + threadIdx.x;
    if (i >= 8 * 1536) return;
    int l = i / 1536, j = i % 1536;
    float v;
    if (j < 512)       v = bq[l * 512 + j] * 0.125f;
    else if (j < 1024) v = bk[l * 512 + j - 512];
    else               v = bv[l * 512 + j - 1024];
    bqkv[i] = v;
}

// ---------------------------------------------------------------------------
extern "C" void kernel_launch(void* const* d_in, const int* in_sizes, int n_in,
                              void* d_out, int out_size, void* d_ws, size_t ws_size,
                              hipStream_t stream)
{
    (void)in_sizes; (void)n_in; (void)out_size; (void)ws_size;
    const float* x    = (const float*)d_in[0];
    const float* ab   = (const float*)d_in[1];
    const float* ln1s = (const float*)d_in[2];
    const float* ln1b = (const float*)d_in[3];
    const float* wq   = (const float*)d_in[4];
    const float* bq   = (const float*)d_in[5];
    const float* wk   = (const float*)d_in[6];
    const float* bk   = (const float*)d_in[7];
    const float* wv   = (const float*)d_in[8];
    const float* bv   = (const float*)d_in[9];
    const float* wo   = (const float*)d_in[10];
    const float* bo   = (const float*)d_in[11];
    const float* ln2s = (const float*)d_in[12];
    const float* ln2b = (const float*)d_in[13];
    const float* w1   = (const float*)d_in[14];
    const float* b1   = (const float*)d_in[15];
    const float* w2   = (const float*)d_in[16];
    const float* b2   = (const float*)d_in[17];

    char* ws = (char*)d_ws;
    float* xf   = (float*)ws;
    bf16* y     = (bf16*)(ws + 16777216);
    bf16* ctx   = y;
    bf16* qkv   = (bf16*)(ws + 16777216 + 8388608);
    bf16* ffn   = qkv;
    bf16* vt    = qkv + (long)8192 * 1536;
    bf16* dbuf  = (bf16*)(ws + 16777216 + 8388608 + 33554432);
    bf16* wqkvT = dbuf + (long)2 * 8192 * 512;
    bf16* woT   = wqkvT + (long)8 * 1536 * 512;
    bf16* w1T   = woT + (long)8 * 512 * 512;
    bf16* w2T   = w1T + (long)8 * 2048 * 512;
    float* bqkv = (float*)(w2T + (long)8 * 512 * 2048);

    hipMemcpyAsync(xf, x, (size_t)8192 * 512 * 4, hipMemcpyDeviceToDevice, stream);
    transpose_k<<<24576, 256, 0, stream>>>(wq, wk, wv, wo, w1, w2, wqkvT, woT, w1T, w2T);
    biasq_k<<<48, 256, 0, stream>>>(bq, bk, bv, bqkv);

    for (int l = 0; l < 8; ++l) {
        if (l == 0)
            ln_k<0><<<2048, 256, 0, stream>>>(xf, nullptr, nullptr, nullptr,
                                              ln1s, ln1b, y);
        else
            ln_k<2><<<2048, 256, 0, stream>>>(xf, xf, dbuf, b2 + (l - 1) * 512,
                                              ln1s + l * 512, ln1b + l * 512, y);
        gemm_k<2><<<dim3(12, 64), 256, 0, stream>>>(
            y, wqkvT + (long)l * 1536 * 512, bqkv + l * 1536, qkv, vt, 512, 1536);
        attn_k<<<1024, 256, 0, stream>>>(qkv, vt, ab, ctx);
        gemm_dk<<<dim3(8, 64, 2), 256, 0, stream>>>(
            ctx, woT + (long)l * 512 * 512, dbuf, 512, 256);
        ln_k<2><<<2048, 256, 0, stream>>>(xf, xf, dbuf, bo + l * 512,
                                          ln2s + l * 512, ln2b + l * 512, y);
        gemm_k<1><<<dim3(16, 64), 256, 0, stream>>>(
            y, w1T + (long)l * 2048 * 512, b1 + l * 2048, ffn, nullptr, 512, 2048);
        gemm_dk<<<dim3(8, 64, 2), 256, 0, stream>>>(
            ffn, w2T + (long)l * 512 * 2048, dbuf, 2048, 1024);
    }
    addout_k<<<2048, 256, 0, stream>>>(xf, dbuf, b2 + 7 * 512, (float*)d_out);
}

// Round 4
// 1378.989 us; speedup vs baseline: 1.0969x; 1.0969x over previous
//
#include <hip/hip_runtime.h>
#include <hip/hip_bf16.h>
#include <math.h>

typedef __bf16 bf16;
typedef __bf16 bf16x8 __attribute__((ext_vector_type(8)));
typedef __bf16 bf16x4 __attribute__((ext_vector_type(4)));
typedef float  f32x4  __attribute__((ext_vector_type(4)));

#define DEV __device__ __forceinline__

DEV f32x4 mfma16(bf16x8 a, bf16x8 b, f32x4 c) {
    return __builtin_amdgcn_mfma_f32_16x16x32_bf16(a, b, c, 0, 0, 0);
}

// async 16B global->LDS. LDS dest is wave-uniform base + lane*16 (linear!).
DEV void gload16(const bf16* g, bf16* l) {
    __builtin_amdgcn_global_load_lds(
        (const __attribute__((address_space(1))) void*)g,
        (__attribute__((address_space(3))) void*)l, 16, 0, 0);
}

// exact-enough erf: Abramowitz-Stegun 7.1.26, |err| <= 1.5e-7 (<< bf16 ulp)
DEV float gelu_f(float v) {
    float xs = v * 0.70710678118654752f;
    float ax = fabsf(xs);
    float t  = 1.0f / (1.0f + 0.3275911f * ax);
    float p  = t * (0.254829592f + t * (-0.284496736f + t * (1.421413741f +
               t * (-1.453152027f + t * 1.061405429f))));
    float er = 1.0f - p * __expf(-ax * ax);
    er = copysignf(er, xs);
    return 0.5f * v * (1.0f + er);
}

// ---------------------------------------------------------------------------
// Wide GEMM: C[M x N] = A[M x K] @ Bt[N x K]^T (+fp32 bias), 128x128, BK=32,
// double-buffered LDS + single barrier per K-step; global_load_lds width=16
// with chunk-XOR swizzle pre-applied to the GLOBAL source (both-sides rule).
// MODE 1: Cb = gelu(acc + bias).
// MODE 2 (QKV): cols <1024 (Q,K) -> Cb[ldC]; V tiles (tn>=1024) -> vt in
//   [(b*8+h)*64+d][n] layout via LDS transpose (coalesced 16B stores).
// ---------------------------------------------------------------------------
template <int MODE>
__global__ __launch_bounds__(256, 3) void gemm_k(
    const bf16* __restrict__ A, const bf16* __restrict__ Bt,
    const float* __restrict__ bias, bf16* __restrict__ Cb,
    bf16* __restrict__ vt, int K, int ldC)
{
    __shared__ bf16 smem[(MODE == 2) ? 17408 : 16384];
    bf16* As = smem;            // [2][4096]
    bf16* Bs = smem + 8192;     // [2][4096]

    const int tid  = threadIdx.x;
    const int lane = tid & 63;
    const int w    = tid >> 6;
    const int wm   = w & 1, wn = w >> 1;
    const long tm  = (long)blockIdx.y * 128;
    const long tn  = (long)blockIdx.x * 128;

    f32x4 acc[4][4] = {};

    const int r0 = tid >> 2;
    const int cc = ((tid & 3) ^ ((r0 >> 1) & 3)) * 8;
    const bf16* Ag = A  + (tm + r0) * K + cc;
    const bf16* Bg = Bt + (tn + r0) * K + cc;
    const long rstep = (long)64 * K;

    int am[4], bn[4];
#pragma unroll
    for (int i = 0; i < 4; ++i) {
        int ra = wm * 64 + i * 16 + (lane & 15);
        am[i]  = ra * 32 + (((lane >> 4) ^ ((ra >> 1) & 3)) * 8);
        int rb = wn * 64 + i * 16 + (lane & 15);
        bn[i]  = rb * 32 + (((lane >> 4) ^ ((rb >> 1) & 3)) * 8);
    }

#define STAGE(buf, kk)                                        \
    do {                                                      \
        gload16(Ag + (kk),         &As[(buf)*4096 + tid*8]);  \
        gload16(Ag + rstep + (kk), &As[(buf)*4096 + 2048 + tid*8]); \
        gload16(Bg + (kk),         &Bs[(buf)*4096 + tid*8]);  \
        gload16(Bg + rstep + (kk), &Bs[(buf)*4096 + 2048 + tid*8]); \
    } while (0)

#define COMPUTE(buf)                                                    \
    do {                                                                \
        bf16x8 a[4], b[4];                                              \
        _Pragma("unroll")                                               \
        for (int i = 0; i < 4; ++i) a[i] = *(const bf16x8*)&As[(buf)*4096 + am[i]]; \
        _Pragma("unroll")                                               \
        for (int i = 0; i < 4; ++i) b[i] = *(const bf16x8*)&Bs[(buf)*4096 + bn[i]]; \
        _Pragma("unroll")                                               \
        for (int mi = 0; mi < 4; ++mi)                                  \
            _Pragma("unroll")                                           \
            for (int ni = 0; ni < 4; ++ni)                              \
                acc[mi][ni] = mfma16(a[mi], b[ni], acc[mi][ni]);        \
    } while (0)

    STAGE(0, 0);
    __syncthreads();
    for (int k0 = 0; k0 < K; k0 += 64) {
        STAGE(1, k0 + 32);
        COMPUTE(0);
        __syncthreads();
        if (k0 + 64 < K) STAGE(0, k0 + 64);
        COMPUTE(1);
        __syncthreads();
    }

    bool vpath = false;
    if constexpr (MODE == 2) vpath = (tn >= 1024);

    if (vpath) {
        bf16* Ct = smem;  // [128 cols][136 rows]
#pragma unroll
        for (int mi = 0; mi < 4; ++mi) {
            const int rowL = wm * 64 + mi * 16 + ((lane >> 4) << 2);
#pragma unroll
            for (int ni = 0; ni < 4; ++ni) {
                const int colL = wn * 64 + ni * 16 + (lane & 15);
                const float bv = bias[tn + colL];
                bf16x4 pk;
#pragma unroll
                for (int r = 0; r < 4; ++r) pk[r] = (bf16)(acc[mi][ni][r] + bv);
                *(bf16x4*)&Ct[colL * 136 + rowL] = pk;
            }
        }
        __syncthreads();
        const int b_blk = (int)(tm >> 8);
        const int nin   = (int)(tm & 255);
        const int cvb   = (int)(tn - 1024);
#pragma unroll
        for (int j = 0; j < 8; ++j) {
            int idx = j * 256 + tid;
            int c   = idx >> 4;
            int nc  = (idx & 15) * 8;
            bf16x8 vv = *(const bf16x8*)&Ct[c * 136 + nc];
            int cv = cvb + c;
            *(bf16x8*)&vt[(((long)b_blk * 8 + (cv >> 6)) * 64 + (cv & 63)) * 256 + nin + nc] = vv;
        }
        return;
    }

#pragma unroll
    for (int mi = 0; mi < 4; ++mi) {
        const long rbase = tm + wm * 64 + mi * 16 + ((lane >> 4) << 2);
#pragma unroll
        for (int ni = 0; ni < 4; ++ni) {
            const long col = tn + wn * 64 + ni * 16 + (lane & 15);
            const float bv = bias[col];
#pragma unroll
            for (int r = 0; r < 4; ++r) {
                float v = acc[mi][ni][r] + bv;
                if constexpr (MODE == 1) v = gelu_f(v);
                Cb[(rbase + r) * (long)ldC + col] = (bf16)v;
            }
        }
    }
#undef STAGE
#undef COMPUTE
}

// ---------------------------------------------------------------------------
// Split-K delta GEMM (N=512): 128x128 tile, grid 4x64x2 (R2 structure --
// R3's BN=64 halved B-reuse and doubled A traffic: -154 us regression).
// ---------------------------------------------------------------------------
__global__ __launch_bounds__(256, 3) void gemm_dk(
    const bf16* __restrict__ A, const bf16* __restrict__ Bt,
    bf16* __restrict__ D, int K, int Ks)
{
    __shared__ bf16 smem[16384];
    bf16* As = smem;
    bf16* Bs = smem + 8192;

    const int tid  = threadIdx.x;
    const int lane = tid & 63;
    const int w    = tid >> 6;
    const int wm   = w & 1, wn = w >> 1;
    const long tm  = (long)blockIdx.y * 128;
    const long tn  = (long)blockIdx.x * 128;
    const int kbase = blockIdx.z * Ks;

    f32x4 acc[4][4] = {};

    const int r0 = tid >> 2;
    const int cc = ((tid & 3) ^ ((r0 >> 1) & 3)) * 8;
    const bf16* Ag = A  + (tm + r0) * K + kbase + cc;
    const bf16* Bg = Bt + (tn + r0) * K + kbase + cc;
    const long rstep = (long)64 * K;

    int am[4], bn[4];
#pragma unroll
    for (int i = 0; i < 4; ++i) {
        int ra = wm * 64 + i * 16 + (lane & 15);
        am[i]  = ra * 32 + (((lane >> 4) ^ ((ra >> 1) & 3)) * 8);
        int rb = wn * 64 + i * 16 + (lane & 15);
        bn[i]  = rb * 32 + (((lane >> 4) ^ ((rb >> 1) & 3)) * 8);
    }

#define STAGE(buf, kk)                                        \
    do {                                                      \
        gload16(Ag + (kk),         &As[(buf)*4096 + tid*8]);  \
        gload16(Ag + rstep + (kk), &As[(buf)*4096 + 2048 + tid*8]); \
        gload16(Bg + (kk),         &Bs[(buf)*4096 + tid*8]);  \
        gload16(Bg + rstep + (kk), &Bs[(buf)*4096 + 2048 + tid*8]); \
    } while (0)

#define COMPUTE(buf)                                                    \
    do {                                                                \
        bf16x8 a[4], b[4];                                              \
        _Pragma("unroll")                                               \
        for (int i = 0; i < 4; ++i) a[i] = *(const bf16x8*)&As[(buf)*4096 + am[i]]; \
        _Pragma("unroll")                                               \
        for (int i = 0; i < 4; ++i) b[i] = *(const bf16x8*)&Bs[(buf)*4096 + bn[i]]; \
        _Pragma("unroll")                                               \
        for (int mi = 0; mi < 4; ++mi)                                  \
            _Pragma("unroll")                                           \
            for (int ni = 0; ni < 4; ++ni)                              \
                acc[mi][ni] = mfma16(a[mi], b[ni], acc[mi][ni]);        \
    } while (0)

    STAGE(0, 0);
    __syncthreads();
    for (int k0 = 0; k0 < Ks; k0 += 64) {
        STAGE(1, k0 + 32);
        COMPUTE(0);
        __syncthreads();
        if (k0 + 64 < Ks) STAGE(0, k0 + 64);
        COMPUTE(1);
        __syncthreads();
    }

    bf16* Dp = D + (long)blockIdx.z * 8192 * 512;
#pragma unroll
    for (int mi = 0; mi < 4; ++mi) {
        const long rbase = tm + wm * 64 + mi * 16 + ((lane >> 4) << 2);
#pragma unroll
        for (int ni = 0; ni < 4; ++ni) {
            const long col = tn + wn * 64 + ni * 16 + (lane & 15);
#pragma unroll
            for (int r = 0; r < 4; ++r)
                Dp[(rbase + r) * 512 + col] = (bf16)acc[mi][ni][r];
        }
    }
#undef STAGE
#undef COMPUTE
}

// ---------------------------------------------------------------------------
// Attention, swapped-QK form: compute S^T = K·Q^T so the C fragment is
// [row=k][col=q]. Bias loads as aligned float4; softmax in-lane + 2 shuffles.
// ---------------------------------------------------------------------------
__global__ __launch_bounds__(256, 4) void attn_k(
    const bf16* __restrict__ qkv, const bf16* __restrict__ vt,
    const float* __restrict__ bias, bf16* __restrict__ ctx)
{
    __shared__ bf16 smem[256 * 72];
    bf16* Ks = smem;

    const int tid = threadIdx.x, lane = tid & 63, w = tid >> 6;
    const int qt = blockIdx.x & 3;
    const int h  = (blockIdx.x >> 2) & 7;
    const int b  = blockIdx.x >> 5;
    const long qkv_base = (long)b * 256 * 1536;

#pragma unroll
    for (int i = 0; i < 8; ++i) {
        int p = i * 256 + tid;
        int n = p >> 3, kk = (p & 7) * 8;
        uint4 v = *(const uint4*)(qkv + qkv_base + (long)n * 1536 + 512 + h * 64 + kk);
        *(uint4*)&Ks[n * 72 + kk] = v;
    }

    const int qr0 = qt * 64 + w * 16;
    bf16x8 aq0, aq1;
    {
        const bf16* g = qkv + qkv_base + (long)(qr0 + (lane & 15)) * 1536 + h * 64 + ((lane >> 4) * 8);
        aq0 = *(const bf16x8*)g;
        aq1 = *(const bf16x8*)(g + 32);
    }
    __syncthreads();

    f32x4 s[16];
    const float* bq_ = bias + ((((long)(b * 8 + h)) * 256 + qr0 + (lane & 15)) * 256)
                     + ((lane >> 4) * 4);
#pragma unroll
    for (int ct = 0; ct < 16; ++ct) {
        f32x4 c = *(const f32x4*)(bq_ + ct * 16);
        bf16x8 k0 = *(const bf16x8*)&Ks[(ct * 16 + (lane & 15)) * 72 + ((lane >> 4) * 8)];
        bf16x8 k1 = *(const bf16x8*)&Ks[(ct * 16 + (lane & 15)) * 72 + 32 + ((lane >> 4) * 8)];
        c = mfma16(k0, aq0, c);   // A = K tile, B = Q tile  ->  C = S^T
        c = mfma16(k1, aq1, c);
        s[ct] = c;
    }

    float m = -1e30f;
#pragma unroll
    for (int ct = 0; ct < 16; ++ct)
#pragma unroll
        for (int r = 0; r < 4; ++r) m = fmaxf(m, s[ct][r]);
    m = fmaxf(m, __shfl_xor(m, 16));
    m = fmaxf(m, __shfl_xor(m, 32));

    float l = 0.f;
#pragma unroll
    for (int ct = 0; ct < 16; ++ct)
#pragma unroll
        for (int r = 0; r < 4; ++r) {
            float p = __expf(s[ct][r] - m);
            s[ct][r] = p;
            l += p;
        }
    l += __shfl_xor(l, 16);
    l += __shfl_xor(l, 32);
    const float linv = 1.0f / l;

    __syncthreads();
    bf16* P = smem + w * (16 * 264);
#pragma unroll
    for (int ct = 0; ct < 16; ++ct) {
        bf16x4 pk;
#pragma unroll
        for (int r = 0; r < 4; ++r) pk[r] = (bf16)(s[ct][r] * linv);
        *(bf16x4*)&P[(lane & 15) * 264 + ct * 16 + ((lane >> 4) * 4)] = pk;
    }

    bf16x8 ap[8];
#pragma unroll
    for (int nk = 0; nk < 8; ++nk)
        ap[nk] = *(const bf16x8*)&P[(lane & 15) * 264 + nk * 32 + (lane >> 4) * 8];

    const bf16* vg = vt + (long)(b * 8 + h) * 64 * 256;
    f32x4 o[4];
#pragma unroll
    for (int dt = 0; dt < 4; ++dt) {
        f32x4 c = {};
#pragma unroll
        for (int nk = 0; nk < 8; ++nk) {
            bf16x8 bv = *(const bf16x8*)&vg[(dt * 16 + (lane & 15)) * 256 + nk * 32 + (lane >> 4) * 8];
            c = mfma16(ap[nk], bv, c);
        }
        o[dt] = c;
    }

#pragma unroll
    for (int dt = 0; dt < 4; ++dt) {
        const int col = h * 64 + dt * 16 + (lane & 15);
#pragma unroll
        for (int r = 0; r < 4; ++r) {
            const long row = (long)b * 256 + qr0 + (lane >> 4) * 4 + r;
            ctx[row * 512 + col] = (bf16)o[dt][r];
        }
    }
}

// ---------------------------------------------------------------------------
// Fused residual-add + LayerNorm. NS = number of bf16 delta slices (0 or 2).
// ---------------------------------------------------------------------------
template <int NS>
__global__ __launch_bounds__(256) void ln_k(
    const float* __restrict__ x, float* __restrict__ xout,
    const bf16* __restrict__ d, const float* __restrict__ rbias,
    const float* __restrict__ sc, const float* __restrict__ bi,
    bf16* __restrict__ y)
{
    const int lane = threadIdx.x & 63;
    const long row = (long)blockIdx.x * 4 + (threadIdx.x >> 6);
    const float* xr = x + row * 512;
    float v[8];
    *(float4*)&v[0] = ((const float4*)xr)[lane * 2];
    *(float4*)&v[4] = ((const float4*)xr)[lane * 2 + 1];
    if constexpr (NS == 2) {
        bf16x8 d0 = *(const bf16x8*)&d[row * 512 + lane * 8];
        bf16x8 d1 = *(const bf16x8*)&d[(long)8192 * 512 + row * 512 + lane * 8];
        float b4[8];
        *(float4*)&b4[0] = ((const float4*)rbias)[lane * 2];
        *(float4*)&b4[4] = ((const float4*)rbias)[lane * 2 + 1];
#pragma unroll
        for (int j = 0; j < 8; ++j)
            v[j] += (float)d0[j] + (float)d1[j] + b4[j];
        float* xo = xout + row * 512;
        ((float4*)xo)[lane * 2]     = *(const float4*)&v[0];
        ((float4*)xo)[lane * 2 + 1] = *(const float4*)&v[4];
    }
    float sum = 0.f;
#pragma unroll
    for (int j = 0; j < 8; ++j) sum += v[j];
#pragma unroll
    for (int off = 1; off < 64; off <<= 1) sum += __shfl_xor(sum, off);
    const float mu = sum * (1.0f / 512.0f);
    float sq = 0.f;
#pragma unroll
    for (int j = 0; j < 8; ++j) { float dd = v[j] - mu; sq += dd * dd; }
#pragma unroll
    for (int off = 1; off < 64; off <<= 1) sq += __shfl_xor(sq, off);
    const float rs = rsqrtf(sq * (1.0f / 512.0f) + 1e-5f);
    bf16* yr = y + row * 512;
#pragma unroll
    for (int j = 0; j < 8; ++j) {
        int c = lane * 8 + j;
        yr[c] = (bf16)((v[j] - mu) * rs * sc[c] + bi[c]);
    }
}

// final: out = xf + d0 + d1 + rbias (fp32)
__global__ __launch_bounds__(256) void addout_k(
    const float* __restrict__ x, const bf16* __restrict__ d,
    const float* __restrict__ rbias, float* __restrict__ out)
{
    const int lane = threadIdx.x & 63;
    const long row = (long)blockIdx.x * 4 + (threadIdx.x >> 6);
    float v[8];
    *(float4*)&v[0] = ((const float4*)(x + row * 512))[lane * 2];
    *(float4*)&v[4] = ((const float4*)(x + row * 512))[lane * 2 + 1];
    bf16x8 d0 = *(const bf16x8*)&d[row * 512 + lane * 8];
    bf16x8 d1 = *(const bf16x8*)&d[(long)8192 * 512 + row * 512 + lane * 8];
    float b4[8];
    *(float4*)&b4[0] = ((const float4*)rbias)[lane * 2];
    *(float4*)&b4[4] = ((const float4*)rbias)[lane * 2 + 1];
#pragma unroll
    for (int j = 0; j < 8; ++j)
        v[j] += (float)d0[j] + (float)d1[j] + b4[j];
    float* o = out + row * 512;
    ((float4*)o)[lane * 2]     = *(const float4*)&v[0];
    ((float4*)o)[lane * 2 + 1] = *(const float4*)&v[4];
}

// ---------------------------------------------------------------------------
// One-shot weight transpose fp32 -> bf16 [N][K] layout (q-scale folded).
// v2: 64(k)x32(n) tile, float4 loads, LDS f32 [64][33], bf16x8 (16B) stores.
// R3 counters: v1 was 2B-scalar-store-bound at 2.3 TB/s.
// ---------------------------------------------------------------------------
__global__ __launch_bounds__(256) void transpose_k(
    const float* __restrict__ wq, const float* __restrict__ wk,
    const float* __restrict__ wv, const float* __restrict__ wo,
    const float* __restrict__ w1, const float* __restrict__ w2,
    bf16* __restrict__ qkvT, bf16* __restrict__ woT,
    bf16* __restrict__ w1T, bf16* __restrict__ w2T)
{
    __shared__ float tile[64][33];
    const int tid = threadIdx.x;
    const int l = blockIdx.x / 1536;
    const int r = blockIdx.x % 1536;

    const float* In = nullptr;
    bf16* Out = nullptr;
    int Nd, tk, tn, rowOff = 0, ldO;
    float scale = 1.0f;
    if (r < 512) {
        const int which = r >> 7, t = r & 127;   // 8 k-tiles x 16 n-tiles
        tk = t >> 4; tn = t & 15; Nd = 512; ldO = 512;
        const long woff = (long)l * 512 * 512;
        if (which == 0)      { In = wq + woff; Out = qkvT + (long)l * 1536 * 512; rowOff = 0;    scale = 0.125f; }
        else if (which == 1) { In = wk + woff; Out = qkvT + (long)l * 1536 * 512; rowOff = 512;  }
        else if (which == 2) { In = wv + woff; Out = qkvT + (long)l * 1536 * 512; rowOff = 1024; }
        else                 { In = wo + woff; Out = woT + woff; }
    } else if (r < 1024) {
        const int t = r - 512;                   // 8 k-tiles x 64 n-tiles
        tk = t >> 6; tn = t & 63; Nd = 2048; ldO = 512;
        In = w1 + (long)l * 512 * 2048; Out = w1T + (long)l * 2048 * 512;
    } else {
        const int t = r - 1024;                  // 32 k-tiles x 16 n-tiles
        tk = t >> 4; tn = t & 15; Nd = 512; ldO = 2048;
        In = w2 + (long)l * 2048 * 512; Out = w2T + (long)l * 512 * 2048;
    }
    const int gk = tk * 64, gn = tn * 32;

    // load: 64 rows x 32 cols, float4 per lane, 2 iters
    {
        const int row = tid >> 3, c4 = (tid & 7) * 4;
#pragma unroll
        for (int j = 0; j < 2; ++j) {
            int rr = row + j * 32;
            float4 v = *(const float4*)&In[(long)(gk + rr) * Nd + gn + c4];
            tile[rr][c4 + 0] = v.x * scale;
            tile[rr][c4 + 1] = v.y * scale;
            tile[rr][c4 + 2] = v.z * scale;
            tile[rr][c4 + 3] = v.w * scale;
        }
    }
    __syncthreads();
    // store: 32 n-rows x 64 k, one bf16x8 (16B) per thread
    {
        const int nn = tid >> 3, kc = (tid & 7) * 8;
        bf16x8 o;
#pragma unroll
        for (int j = 0; j < 8; ++j) o[j] = (bf16)tile[kc + j][nn];
        *(bf16x8*)&Out[(long)(rowOff + gn + nn) * ldO + gk + kc] = o;
    }
}

__global__ void biasq_k(const float* __restrict__ bq, const float* __restrict__ bk,
                        const float* __restrict__ bv, float* __restrict__ bqkv)
{
    int i = blockIdx.x * 256 + threadIdx.x;
    if (i >= 8 * 1536) return;
    int l = i / 1536, j = i % 1536;
    float v;
    if (j < 512)       v = bq[l * 512 + j] * 0.125f;
    else if (j < 1024) v = bk[l * 512 + j - 512];
    else               v = bv[l * 512 + j - 1024];
    bqkv[i] = v;
}

// ---------------------------------------------------------------------------
extern "C" void kernel_launch(void* const* d_in, const int* in_sizes, int n_in,
                              void* d_out, int out_size, void* d_ws, size_t ws_size,
                              hipStream_t stream)
{
    (void)in_sizes; (void)n_in; (void)out_size; (void)ws_size;
    const float* x    = (const float*)d_in[0];
    const float* ab   = (const float*)d_in[1];
    const float* ln1s = (const float*)d_in[2];
    const float* ln1b = (const float*)d_in[3];
    const float* wq   = (const float*)d_in[4];
    const float* bq   = (const float*)d_in[5];
    const float* wk   = (const float*)d_in[6];
    const float* bk   = (const float*)d_in[7];
    const float* wv   = (const float*)d_in[8];
    const float* bv   = (const float*)d_in[9];
    const float* wo   = (const float*)d_in[10];
    const float* bo   = (const float*)d_in[11];
    const float* ln2s = (const float*)d_in[12];
    const float* ln2b = (const float*)d_in[13];
    const float* w1   = (const float*)d_in[14];
    const float* b1   = (const float*)d_in[15];
    const float* w2   = (const float*)d_in[16];
    const float* b2   = (const float*)d_in[17];

    char* ws = (char*)d_ws;
    float* xf   = (float*)ws;
    bf16* y     = (bf16*)(ws + 16777216);
    bf16* ctx   = y;
    bf16* qkv   = (bf16*)(ws + 16777216 + 8388608);
    bf16* ffn   = qkv;
    bf16* vt    = qkv + (long)8192 * 1536;
    bf16* dbuf  = (bf16*)(ws + 16777216 + 8388608 + 33554432);
    bf16* wqkvT = dbuf + (long)2 * 8192 * 512;
    bf16* woT   = wqkvT + (long)8 * 1536 * 512;
    bf16* w1T   = woT + (long)8 * 512 * 512;
    bf16* w2T   = w1T + (long)8 * 2048 * 512;
    float* bqkv = (float*)(w2T + (long)8 * 512 * 2048);

    hipMemcpyAsync(xf, x, (size_t)8192 * 512 * 4, hipMemcpyDeviceToDevice, stream);
    transpose_k<<<12288, 256, 0, stream>>>(wq, wk, wv, wo, w1, w2, wqkvT, woT, w1T, w2T);
    biasq_k<<<48, 256, 0, stream>>>(bq, bk, bv, bqkv);

    for (int l = 0; l < 8; ++l) {
        if (l == 0)
            ln_k<0><<<2048, 256, 0, stream>>>(xf, nullptr, nullptr, nullptr,
                                              ln1s, ln1b, y);
        else
            ln_k<2><<<2048, 256, 0, stream>>>(xf, xf, dbuf, b2 + (l - 1) * 512,
                                              ln1s + l * 512, ln1b + l * 512, y);
        gemm_k<2><<<dim3(12, 64), 256, 0, stream>>>(
            y, wqkvT + (long)l * 1536 * 512, bqkv + l * 1536, qkv, vt, 512, 1536);
        attn_k<<<1024, 256, 0, stream>>>(qkv, vt, ab, ctx);
        gemm_dk<<<dim3(4, 64, 2), 256, 0, stream>>>(
            ctx, woT + (long)l * 512 * 512, dbuf, 512, 256);
        ln_k<2><<<2048, 256, 0, stream>>>(xf, xf, dbuf, bo + l * 512,
                                          ln2s + l * 512, ln2b + l * 512, y);
        gemm_k<1><<<dim3(16, 64), 256, 0, stream>>>(
            y, w1T + (long)l * 2048 * 512, b1 + l * 2048, ffn, nullptr, 512, 2048);
        gemm_dk<<<dim3(4, 64, 2), 256, 0, stream>>>(
            ffn, w2T + (long)l * 512 * 2048, dbuf, 2048, 1024);
    }
    addout_k<<<2048, 256, 0, stream>>>(xf, dbuf, b2 + 7 * 512, (float*)d_out);
}